// Round 8
// baseline (57.485 us; speedup 1.0000x reference)
//
#include <hip/hip_runtime.h>
#include <cstdint>

#define TOK 2048
#define EMB 768
#define WIN 64
#define TCN (TOK / 16) // 128 token tiles (16-row)
#define DCN (EMB / 32) // 24 d-chunks (32-col)

typedef __attribute__((ext_vector_type(8))) __bf16 bf16x8;
typedef __attribute__((ext_vector_type(4))) float f32x4;

static __device__ __forceinline__ unsigned short f2bf(float f) {
  uint32_t x = __float_as_uint(f);
  uint32_t r = (x + 0x7fffu + ((x >> 16) & 1u)) >> 16;  // RNE
  return (unsigned short)r;
}

static __device__ __forceinline__ void gload_lds16(const void* g, void* l) {
  __builtin_amdgcn_global_load_lds(
      (const __attribute__((address_space(1))) uint32_t*)g,
      (__attribute__((address_space(3))) uint32_t*)l, 16, 0, 0);
}

// ---------------- prep (one kernel, z-dispatch) ----------------
// z=0: Wq,Wk -> bf16 flat (row-major; no transpose needed for M-GEMM)
// z=1: Wv -> transposed bf16 WvT[d][e]
// z=2: key -> tiled bf16 k_t [tok/16][d/32][16][32]
__global__ __launch_bounds__(256) void prep(
    const float* __restrict__ Wq, const float* __restrict__ Wk,
    const float* __restrict__ Wv, const float* __restrict__ key,
    unsigned short* __restrict__ Wqb, unsigned short* __restrict__ Wkb,
    unsigned short* __restrict__ WvT, unsigned short* __restrict__ k_t) {
  __shared__ float t[32][33];
  const int z = blockIdx.z, bx = blockIdx.x, tid = threadIdx.x;
  if (z == 0) {
    const int NW4 = EMB * EMB / 4;  // 147456 float4 per W
    int i = bx * 256 + tid;
    if (i >= 2 * NW4) return;
    const float4* src = (const float4*)((i < NW4) ? Wq : Wk);
    unsigned short* dst = (i < NW4) ? Wqb : Wkb;
    const int loc = (i < NW4) ? i : i - NW4;
    const float4 x = src[loc];
    ushort4 h;
    h.x = f2bf(x.x); h.y = f2bf(x.y); h.z = f2bf(x.z); h.w = f2bf(x.w);
    ((ushort4*)dst)[loc] = h;
  } else if (z == 1) {
    if (bx >= 576) return;
    const int d0 = (bx % 24) * 32, e0 = (bx / 24) * 32;
    const int tx = tid & 31, ty = tid >> 5;  // (32,8)
#pragma unroll
    for (int r = 0; r < 4; ++r)
      t[ty + r * 8][tx] = Wv[(size_t)(e0 + ty + r * 8) * EMB + d0 + tx];
    __syncthreads();
#pragma unroll
    for (int r = 0; r < 4; ++r) {
      const int dl = ty + r * 8, el = tx;
      WvT[(size_t)(d0 + dl) * EMB + e0 + el] = f2bf(t[el][dl]);
    }
  } else {
    if (bx >= 128) return;
    const int tt = bx;  // token tile
    for (int u = tid; u < 16 * EMB / 4; u += 256) {
      const int row = u / (EMB / 4), d = (u % (EMB / 4)) * 4;
      const float4 x = *(const float4*)(key + (size_t)(tt * 16 + row) * EMB + d);
      ushort4 h;
      h.x = f2bf(x.x); h.y = f2bf(x.y); h.z = f2bf(x.z); h.w = f2bf(x.w);
      *(ushort4*)&k_t[(((size_t)tt * DCN + (d >> 5)) * 16 + row) * 32 + (d & 31)] = h;
    }
  }
}

// ---------------- mgemm: Mt = Wk @ Wq^T (bf16, 768x768) ----------------
// Mt[e2][e1] = sum_d Wk[e2][d] Wq[e1][d]. Both operands row-major, K=d
// contiguous -> direct gload_lds staging. Output row-major bf16 = M^T,
// which is exactly the B-operand layout proj2 needs for q' = query @ M.
__global__ __launch_bounds__(256) void mgemm(
    const unsigned short* __restrict__ Wkb, const unsigned short* __restrict__ Wqb,
    unsigned short* __restrict__ Mt) {
  const int bn0 = blockIdx.x * 128;  // e1
  const int bm0 = blockIdx.y * 64;   // e2
  const int tid = threadIdx.x, lane = tid & 63, w = tid >> 6;
  const int wr = w >> 1, wc = w & 1;

  __shared__ unsigned short lA[64 * 32];
  __shared__ unsigned short lB[128 * 32];

  f32x4 acc[2][4] = {};
  const int sr = lane >> 2, sk = (lane & 3) * 8;

  for (int kk = 0; kk < EMB; kk += 32) {
    __syncthreads();
#pragma unroll
    for (int c = 0; c < 3; ++c) {
      const int chunk = w + c * 4;
      if (chunk < 4) {
        gload_lds16(Wkb + (size_t)(bm0 + chunk * 16 + sr) * EMB + kk + sk,
                    (char*)lA + chunk * 1024);
      } else {
        const int bc = chunk - 4;
        gload_lds16(Wqb + (size_t)(bn0 + bc * 16 + sr) * EMB + kk + sk,
                    (char*)lB + bc * 1024);
      }
    }
    __syncthreads();

    bf16x8 af[2], bfr[4];
#pragma unroll
    for (int m = 0; m < 2; ++m)
      af[m] = *(const bf16x8*)&lA[(wr * 32 + m * 16 + (lane & 15)) * 32 +
                                  (lane >> 4) * 8];
#pragma unroll
    for (int n = 0; n < 4; ++n)
      bfr[n] = *(const bf16x8*)&lB[(wc * 64 + n * 16 + (lane & 15)) * 32 +
                                   (lane >> 4) * 8];
#pragma unroll
    for (int m = 0; m < 2; ++m)
#pragma unroll
      for (int n = 0; n < 4; ++n)
        acc[m][n] = __builtin_amdgcn_mfma_f32_16x16x32_bf16(af[m], bfr[n],
                                                            acc[m][n], 0, 0, 0);
  }

  const int l15 = lane & 15, l4 = lane >> 4;
#pragma unroll
  for (int m = 0; m < 2; ++m) {
    const int row = bm0 + wr * 32 + m * 16 + l4 * 4;
#pragma unroll
    for (int n = 0; n < 4; ++n) {
      const int col = bn0 + wc * 64 + n * 16 + l15;
#pragma unroll
      for (int r = 0; r < 4; ++r)
        Mt[(size_t)(row + r) * EMB + col] = f2bf(acc[m][n][r]);
    }
  }
}

// ---------------- proj2: q' = query@M, v = value@Wv ----------------
// A staged fp32->bf16 in-reg with one-step prefetch rotation (load for
// kk+32 issued before barrier-2; cvt during MFMA phase). B via gload_lds.
// z=0: B=Mt, epilogue -> q_t tiled.  z=1: B=WvT, epilogue -> vT_p panels.
__global__ __launch_bounds__(256) void proj2(
    const float* __restrict__ query, const float* __restrict__ value,
    const unsigned short* __restrict__ Mt, const unsigned short* __restrict__ WvT,
    unsigned short* __restrict__ q_t, unsigned short* __restrict__ vT_p) {
  const int z = blockIdx.z;
  const float* __restrict__ Af = (z == 0) ? query : value;
  const unsigned short* __restrict__ Bh = (z == 0) ? Mt : WvT;
  const int bn0 = blockIdx.x * 128;  // output col
  const int bm0 = blockIdx.y * 64;   // output row (token)
  const int tid = threadIdx.x, lane = tid & 63, w = tid >> 6;
  const int wr = w >> 1, wc = w & 1;

  __shared__ unsigned short lA[64 * 32];
  __shared__ unsigned short lB[128 * 32];

  f32x4 acc[2][4] = {};
  const int sr = lane >> 2, sk = (lane & 3) * 8;
  const int arow = tid >> 2, aks = (tid & 3) * 8;
  const float* __restrict__ abase = Af + (size_t)(bm0 + arow) * EMB + aks;

  float4 x0 = *(const float4*)(abase);
  float4 x1 = *(const float4*)(abase + 4);

  for (int kk = 0; kk < EMB; kk += 32) {
    bf16x8 av;
    av[0] = (__bf16)x0.x; av[1] = (__bf16)x0.y;
    av[2] = (__bf16)x0.z; av[3] = (__bf16)x0.w;
    av[4] = (__bf16)x1.x; av[5] = (__bf16)x1.y;
    av[6] = (__bf16)x1.z; av[7] = (__bf16)x1.w;
    __syncthreads();  // previous compute done before overwrite
    *(bf16x8*)&lA[arow * 32 + aks] = av;
#pragma unroll
    for (int c = 0; c < 2; ++c) {
      const int bc = w * 2 + c;
      gload_lds16(Bh + (size_t)(bn0 + bc * 16 + sr) * EMB + kk + sk,
                  (char*)lB + bc * 1024);
    }
    if (kk + 32 < EMB) {  // prefetch next A (drains with B at barrier)
      x0 = *(const float4*)(abase + kk + 32);
      x1 = *(const float4*)(abase + kk + 36);
    }
    __syncthreads();  // ds_write + gload visible

    bf16x8 af[2], bfr[4];
#pragma unroll
    for (int m = 0; m < 2; ++m)
      af[m] = *(const bf16x8*)&lA[(wr * 32 + m * 16 + (lane & 15)) * 32 +
                                  (lane >> 4) * 8];
#pragma unroll
    for (int n = 0; n < 4; ++n)
      bfr[n] = *(const bf16x8*)&lB[(wc * 64 + n * 16 + (lane & 15)) * 32 +
                                   (lane >> 4) * 8];
#pragma unroll
    for (int m = 0; m < 2; ++m)
#pragma unroll
      for (int n = 0; n < 4; ++n)
        acc[m][n] = __builtin_amdgcn_mfma_f32_16x16x32_bf16(af[m], bfr[n],
                                                            acc[m][n], 0, 0, 0);
  }

  const int l15 = lane & 15, l4 = lane >> 4;
  if (z == 1) {
#pragma unroll
    for (int m = 0; m < 2; ++m) {
      const int tok0 = bm0 + wr * 32 + m * 16 + l4 * 4;
#pragma unroll
      for (int n = 0; n < 4; ++n) {
        const int d = bn0 + wc * 64 + n * 16 + l15;
        ushort4 pk;
        pk.x = f2bf(acc[m][n][0]); pk.y = f2bf(acc[m][n][1]);
        pk.z = f2bf(acc[m][n][2]); pk.w = f2bf(acc[m][n][3]);
        *(ushort4*)&vT_p[(((size_t)(tok0 >> 5) * EMB + d) << 5) + (tok0 & 31)] = pk;
      }
    }
  } else {
#pragma unroll
    for (int m = 0; m < 2; ++m) {
      const int tok0 = bm0 + wr * 32 + m * 16 + l4 * 4;
#pragma unroll
      for (int n = 0; n < 4; ++n) {
        const int d = bn0 + wc * 64 + n * 16 + l15;
        const size_t base =
            (((size_t)(tok0 >> 4) * DCN + (d >> 5)) * 16) * 32 + (d & 31);
#pragma unroll
        for (int r = 0; r < 4; ++r)
          q_t[base + (size_t)((tok0 & 15) + r) * 32] = f2bf(acc[m][n][r]);
      }
    }
  }
}

// ---------------- attn stage 1: scores -> exp -> P tiles + partial sums ----
__global__ __launch_bounds__(192) void attn_S(
    const unsigned short* __restrict__ k_t, const unsigned short* __restrict__ q_t,
    unsigned short* __restrict__ Pg, float* __restrict__ Ssum) {
  const int bid = ((int)blockIdx.x & 7) * 64 + ((int)blockIdx.x >> 3);  // XCD swz
  const int qt = bid >> 2, ks = bid & 3;
  const int lane = threadIdx.x & 63, w = threadIdx.x >> 6;  // 0..2
  const int nt = ks * 3 + w;                                // 0..11
  const int l15 = lane & 15, l4 = lane >> 4;
  const int t0 = qt * 16;
  const int js0 = (t0 - 64) & ~31;  // 32-aligned slot base (maybe <0)
  const int foff = l15 * 32 + l4 * 8;

  const size_t a_base = (size_t)qt * DCN * 512 + foff;
  const int ttile = min(max((js0 >> 4) + nt, 0), TCN - 1);  // clamp; masked
  const size_t b_base = (size_t)ttile * DCN * 512 + foff;

  f32x4 s = {};
#pragma unroll 8
  for (int kk = 0; kk < DCN; ++kk) {
    const bf16x8 ah = *(const bf16x8*)&q_t[a_base + (size_t)kk * 512];
    const bf16x8 bh = *(const bf16x8*)&k_t[b_base + (size_t)kk * 512];
    s = __builtin_amdgcn_mfma_f32_16x16x32_bf16(ah, bh, s, 0, 0, 0);
  }

  const float SC = 0.03608439182435161f;  // 768^-0.5
  const int j = js0 + nt * 16 + l15;
  const int qrow0 = t0 + l4 * 4;
  const int c = nt >> 1, colb = (nt & 1) * 16 + l15;

  float e[4];
#pragma unroll
  for (int r = 0; r < 4; ++r) {
    const int t = qrow0 + r;
    const bool ok = (j >= 0) && (j < TOK) && (j >= t - WIN) && (j <= t + WIN);
    e[r] = ok ? __expf(s[r] * SC) : 0.0f;
  }
#pragma unroll
  for (int r = 0; r < 4; ++r) {
    float sm = e[r];
#pragma unroll
    for (int off = 1; off < 16; off <<= 1) sm += __shfl_xor(sm, off);
    if (l15 == 0) Ssum[qt * 192 + nt * 16 + l4 * 4 + r] = sm;
  }
#pragma unroll
  for (int r = 0; r < 4; ++r)
    Pg[(((size_t)qt * 6 + c) * 16 + (l4 * 4 + r)) * 32 + colb] = f2bf(e[r]);
}

// ---------------- attn stage 2: PV + normalize ----------------
__global__ __launch_bounds__(192) void attn_PV(
    const unsigned short* __restrict__ Pg, const float* __restrict__ Ssum,
    const unsigned short* __restrict__ vT_p, float* __restrict__ out) {
  const int bid = ((int)blockIdx.x & 7) * 64 + ((int)blockIdx.x >> 3);  // XCD swz
  const int qt = bid >> 2, ds = bid & 3;
  const int tid = threadIdx.x;
  const int lane = tid & 63, w = tid >> 6;
  const int l15 = lane & 15, l4 = lane >> 4;
  const int t0 = qt * 16;
  const int js0 = (t0 - 64) & ~31;

  __shared__ float ssum_l[192];
  __shared__ float rcp_l[16];

  ssum_l[tid] = Ssum[qt * 192 + tid];
  __syncthreads();
  if (tid < 16) {
    float s = 0.f;
#pragma unroll
    for (int i = 0; i < 12; ++i) s += ssum_l[i * 16 + tid];
    const int t = t0 + tid;
    const int len = min(TOK, t + WIN + 1) - max(0, t - WIN);
    rcp_l[tid] = 1.0f / (s * (float)len);
  }

  f32x4 o[4] = {};
  const int c0 = js0 >> 5;
#pragma unroll
  for (int kc = 0; kc < 6; ++kc) {
    const bf16x8 pa =
        *(const bf16x8*)&Pg[(((size_t)qt * 6 + kc) * 16 + l15) * 32 + l4 * 8];
    const int cc = min(max(c0 + kc, 0), TOK / 32 - 1);  // clamp; P=0 masks
    const size_t vb = (size_t)cc * (EMB * 32);
#pragma unroll
    for (int n = 0; n < 4; ++n) {
      const int d = ds * 192 + w * 64 + n * 16 + l15;
      const bf16x8 vbf = *(const bf16x8*)&vT_p[vb + (size_t)d * 32 + l4 * 8];
      o[n] = __builtin_amdgcn_mfma_f32_16x16x32_bf16(pa, vbf, o[n], 0, 0, 0);
    }
  }
  __syncthreads();  // rcp_l ready

  const int qrow0 = t0 + l4 * 4;
  float rr[4];
#pragma unroll
  for (int r = 0; r < 4; ++r) rr[r] = rcp_l[l4 * 4 + r];
#pragma unroll
  for (int n = 0; n < 4; ++n) {
    const int d = ds * 192 + w * 64 + n * 16 + l15;
#pragma unroll
    for (int r = 0; r < 4; ++r)
      out[(size_t)(qrow0 + r) * EMB + d] = o[n][r] * rr[r];
  }
}

extern "C" void kernel_launch(void* const* d_in, const int* in_sizes, int n_in,
                              void* d_out, int out_size, void* d_ws, size_t ws_size,
                              hipStream_t stream) {
  const float* key = (const float*)d_in[0];
  const float* value = (const float*)d_in[1];
  const float* query = (const float*)d_in[2];
  const float* Wk = (const float*)d_in[3];
  const float* Wv = (const float*)d_in[4];
  const float* Wq = (const float*)d_in[5];

  // ws layout (~15 MB): Wqb | Wkb | WvT | Mt | k_t | q_t | vT_p | Pg | Ssum
  unsigned short* ws = (unsigned short*)d_ws;
  const size_t NW = (size_t)EMB * EMB;   // 589824
  const size_t NM = (size_t)TOK * EMB;   // 1572864
  unsigned short* Wqb = ws;
  unsigned short* Wkb = Wqb + NW;
  unsigned short* WvT = Wkb + NW;
  unsigned short* Mt = WvT + NW;
  unsigned short* k_t = Mt + NW;
  unsigned short* q_t = k_t + NM;
  unsigned short* vT_p = q_t + NM;
  unsigned short* Pg = vT_p + NM;                           // 393216 u16
  float* Ssum = (float*)(Pg + (size_t)128 * 6 * 16 * 32);   // 24576 f32
  float* out = (float*)d_out;

  prep<<<dim3(1152, 1, 3), 256, 0, stream>>>(Wq, Wk, Wv, key, Wqb, Wkb, WvT, k_t);
  mgemm<<<dim3(6, 12), 256, 0, stream>>>(Wkb, Wqb, Mt);
  proj2<<<dim3(EMB / 128, TOK / 64, 2), 256, 0, stream>>>(
      query, value, Mt, WvT, q_t, vT_p);
  attn_S<<<512, 192, 0, stream>>>(k_t, q_t, Pg, Ssum);
  attn_PV<<<512, 192, 0, stream>>>(Pg, Ssum, vT_p, out);
}

// Round 9
// 46.768 us; speedup vs baseline: 1.2291x; 1.2291x over previous
//
#include <hip/hip_runtime.h>
#include <cstdint>

#define TOK 2048
#define EMB 768
#define WIN 64
#define TCN (TOK / 16) // 128 token tiles (16-row)
#define DCN (EMB / 32) // 24 d-chunks (32-col)

typedef __attribute__((ext_vector_type(8))) __bf16 bf16x8;
typedef __attribute__((ext_vector_type(4))) float f32x4;

static __device__ __forceinline__ unsigned short f2bf(float f) {
  uint32_t x = __float_as_uint(f);
  uint32_t r = (x + 0x7fffu + ((x >> 16) & 1u)) >> 16;  // RNE
  return (unsigned short)r;
}

static __device__ __forceinline__ void gload_lds16(const void* g, void* l) {
  __builtin_amdgcn_global_load_lds(
      (const __attribute__((address_space(1))) uint32_t*)g,
      (__attribute__((address_space(3))) uint32_t*)l, 16, 0, 0);
}

// ---------------- prep: weights -> transposed bf16 ----------------
__global__ void cvt_wT(const float* __restrict__ w0, const float* __restrict__ w1,
                       const float* __restrict__ w2,
                       unsigned short* __restrict__ hiT) {
  __shared__ float t[32][33];
  const int z = blockIdx.z;
  const float* w = (z == 0) ? w0 : (z == 1) ? w1 : w2;
  const int d0 = blockIdx.x * 32, e0 = blockIdx.y * 32;
  const int tx = threadIdx.x, ty = threadIdx.y;  // (32,8)
#pragma unroll
  for (int r = 0; r < 4; ++r)
    t[ty + r * 8][tx] = w[(size_t)(e0 + ty + r * 8) * EMB + d0 + tx];
  __syncthreads();
#pragma unroll
  for (int r = 0; r < 4; ++r) {
    const int dl = ty + r * 8, el = tx;
    const float f = t[el][dl];  // = W[e0+el][d0+dl]
    hiT[(size_t)z * EMB * EMB + (size_t)(d0 + dl) * EMB + e0 + el] = f2bf(f);
  }
}

// ---------------- projections: bf16 MFMA GEMM, A staged as RAW fp32 --------
// C = A@W. A is staged fp32 via global_load_lds (fire-and-forget, drains at
// the same barrier as B — no serial cvt chain). fp32->bf16 happens at the
// LDS->fragment read (2x ds_read_b128 + casts, hidden under MFMA).
// Source-chunk XOR swizzle (chunk ^ (row&7)) at staging + same XOR on read
// breaks the 16-way fp32 column bank conflict (rule #21 involution).
// Epilogue writes MFMA-native layouts:
//   z=0 (k), z=2 (q): bf16 tiled [tok/16][d/32][16][32]
//   z=1 (v): bf16 V^T panels [tok/32][768][32]
__global__ __launch_bounds__(256) void proj_gemm(
    const float* __restrict__ key, const float* __restrict__ value,
    const float* __restrict__ query, const unsigned short* __restrict__ WT,
    unsigned short* __restrict__ k_t, unsigned short* __restrict__ vT_p,
    unsigned short* __restrict__ q_t) {
  const int z = blockIdx.z;
  const float* __restrict__ Af = (z == 0) ? key : (z == 1) ? value : query;
  const int bn0 = blockIdx.x * 128;  // output col (D)
  const int bm0 = blockIdx.y * 64;   // output row (token)
  const int tid = threadIdx.x, lane = tid & 63, w = tid >> 6;
  const int wr = w >> 1, wc = w & 1;

  __shared__ float lAf[64 * 32];            // 8KB fp32 A (chunk-swizzled)
  __shared__ unsigned short lB[128 * 32];   // 8KB bf16 B

  const unsigned short* Bh = WT + (size_t)z * EMB * EMB;

  f32x4 acc[2][4] = {};

  const int sr = lane >> 2;        // B staging: row within 16-row chunk
  const int sk = (lane & 3) * 8;   // B staging: k element offset (16B)
  const int arl = lane >> 3;       // A staging: row within 8-row group
  const int ach = lane & 7;        // A staging: 16B chunk slot in row
  const int l15 = lane & 15, l4 = lane >> 4;

  for (int kk = 0; kk < EMB; kk += 32) {
    __syncthreads();  // previous compute done before overwrite
    // A: fp32 direct global_load_lds, 8 x 1KB loads (2 per wave).
    // lds[row][chunk] = global[row][chunk ^ (row&7)]  (16B chunks)
#pragma unroll
    for (int c = 0; c < 2; ++c) {
      const int li = w * 2 + c;          // 0..7
      const int row = li * 8 + arl;      // 0..63
      const int scol = (ach ^ (row & 7)) * 4;  // float col
      gload_lds16(Af + (size_t)(bm0 + row) * EMB + kk + scol,
                  (char*)lAf + li * 1024);
    }
    // B: bf16 global_load_lds (linear), 8 x 1KB loads (2 per wave)
#pragma unroll
    for (int c = 0; c < 2; ++c) {
      const int bc = w * 2 + c;
      gload_lds16(Bh + (size_t)(bn0 + bc * 16 + sr) * EMB + kk + sk,
                  (char*)lB + bc * 1024);
    }
    __syncthreads();  // both gload streams drained (vmcnt0)

    bf16x8 af[2], bfr[4];
#pragma unroll
    for (int m = 0; m < 2; ++m) {
      const int row = wr * 32 + m * 16 + l15;
      const int x0 = l4 * 2;  // global chunk pair for k = l4*8..+8
      const float4 f0 =
          *(const float4*)&lAf[row * 32 + ((x0 ^ (row & 7)) * 4)];
      const float4 f1 =
          *(const float4*)&lAf[row * 32 + (((x0 + 1) ^ (row & 7)) * 4)];
      bf16x8 av;
      av[0] = (__bf16)f0.x; av[1] = (__bf16)f0.y;
      av[2] = (__bf16)f0.z; av[3] = (__bf16)f0.w;
      av[4] = (__bf16)f1.x; av[5] = (__bf16)f1.y;
      av[6] = (__bf16)f1.z; av[7] = (__bf16)f1.w;
      af[m] = av;
    }
#pragma unroll
    for (int n = 0; n < 4; ++n)
      bfr[n] = *(const bf16x8*)&lB[(wc * 64 + n * 16 + l15) * 32 + l4 * 8];
#pragma unroll
    for (int m = 0; m < 2; ++m)
#pragma unroll
      for (int n = 0; n < 4; ++n)
        acc[m][n] = __builtin_amdgcn_mfma_f32_16x16x32_bf16(af[m], bfr[n],
                                                            acc[m][n], 0, 0, 0);
  }

  // ---- epilogue: write MFMA-native layouts ----
  if (z == 1) {
#pragma unroll
    for (int m = 0; m < 2; ++m) {
      const int tok0 = bm0 + wr * 32 + m * 16 + l4 * 4;
#pragma unroll
      for (int n = 0; n < 4; ++n) {
        const int d = bn0 + wc * 64 + n * 16 + l15;
        ushort4 pk;
        pk.x = f2bf(acc[m][n][0]); pk.y = f2bf(acc[m][n][1]);
        pk.z = f2bf(acc[m][n][2]); pk.w = f2bf(acc[m][n][3]);
        *(ushort4*)&vT_p[(((size_t)(tok0 >> 5) * EMB + d) << 5) + (tok0 & 31)] = pk;
      }
    }
  } else {
    unsigned short* __restrict__ dh = (z == 0) ? k_t : q_t;
#pragma unroll
    for (int m = 0; m < 2; ++m) {
      const int tok0 = bm0 + wr * 32 + m * 16 + l4 * 4;
#pragma unroll
      for (int n = 0; n < 4; ++n) {
        const int d = bn0 + wc * 64 + n * 16 + l15;
        const size_t base =
            (((size_t)(tok0 >> 4) * DCN + (d >> 5)) * 16) * 32 + (d & 31);
#pragma unroll
        for (int r = 0; r < 4; ++r)
          dh[base + (size_t)((tok0 & 15) + r) * 32] = f2bf(acc[m][n][r]);
      }
    }
  }
}

// ---------------- attn stage 1: scores -> exp -> P tiles + partial sums ----
// grid 512 = (qt 0..127) x (ksplit 0..3); 3 waves, wave owns N-tile
// nt = ks*3+w of 12. No max-subtraction (scores ~N(0,1), exp safe in fp32).
// P -> A-tile layout [qt*6+c][16 q][32 slot] bf16; partial sums -> Ssum.
__global__ __launch_bounds__(192) void attn_S(
    const unsigned short* __restrict__ k_t, const unsigned short* __restrict__ q_t,
    unsigned short* __restrict__ Pg, float* __restrict__ Ssum) {
  const int bid = ((int)blockIdx.x & 7) * 64 + ((int)blockIdx.x >> 3);  // XCD swz
  const int qt = bid >> 2, ks = bid & 3;
  const int lane = threadIdx.x & 63, w = threadIdx.x >> 6;  // 0..2
  const int nt = ks * 3 + w;                                // 0..11
  const int l15 = lane & 15, l4 = lane >> 4;
  const int t0 = qt * 16;
  const int js0 = (t0 - 64) & ~31;  // 32-aligned slot base (maybe <0)
  const int foff = l15 * 32 + l4 * 8;

  const size_t a_base = (size_t)qt * DCN * 512 + foff;
  const int ttile = min(max((js0 >> 4) + nt, 0), TCN - 1);  // clamp; masked
  const size_t b_base = (size_t)ttile * DCN * 512 + foff;

  f32x4 s = {};
#pragma unroll 8
  for (int kk = 0; kk < DCN; ++kk) {
    const bf16x8 ah = *(const bf16x8*)&q_t[a_base + (size_t)kk * 512];
    const bf16x8 bh = *(const bf16x8*)&k_t[b_base + (size_t)kk * 512];
    s = __builtin_amdgcn_mfma_f32_16x16x32_bf16(ah, bh, s, 0, 0, 0);
  }

  const float SC = 0.03608439182435161f;  // 768^-0.5
  const int j = js0 + nt * 16 + l15;
  const int qrow0 = t0 + l4 * 4;
  const int c = nt >> 1, colb = (nt & 1) * 16 + l15;

  float e[4];
#pragma unroll
  for (int r = 0; r < 4; ++r) {
    const int t = qrow0 + r;
    const bool ok = (j >= 0) && (j < TOK) && (j >= t - WIN) && (j <= t + WIN);
    e[r] = ok ? __expf(s[r] * SC) : 0.0f;
  }
#pragma unroll
  for (int r = 0; r < 4; ++r) {
    float sm = e[r];
#pragma unroll
    for (int off = 1; off < 16; off <<= 1) sm += __shfl_xor(sm, off);
    if (l15 == 0) Ssum[qt * 192 + nt * 16 + l4 * 4 + r] = sm;
  }
#pragma unroll
  for (int r = 0; r < 4; ++r)
    Pg[(((size_t)qt * 6 + c) * 16 + (l4 * 4 + r)) * 32 + colb] = f2bf(e[r]);
}

// ---------------- attn stage 2: PV + normalize ----------------
// grid 512 = (qt 0..127) x (dsplit 0..3); 3 waves, wave owns 64 d-cols.
// out[q][d] = (sum_k P[q][k] V[k][d]) / (rowsum * L).
__global__ __launch_bounds__(192) void attn_PV(
    const unsigned short* __restrict__ Pg, const float* __restrict__ Ssum,
    const unsigned short* __restrict__ vT_p, float* __restrict__ out) {
  const int bid = ((int)blockIdx.x & 7) * 64 + ((int)blockIdx.x >> 3);  // XCD swz
  const int qt = bid >> 2, ds = bid & 3;
  const int tid = threadIdx.x;
  const int lane = tid & 63, w = tid >> 6;
  const int l15 = lane & 15, l4 = lane >> 4;
  const int t0 = qt * 16;
  const int js0 = (t0 - 64) & ~31;

  __shared__ float ssum_l[192];
  __shared__ float rcp_l[16];

  ssum_l[tid] = Ssum[qt * 192 + tid];
  __syncthreads();
  if (tid < 16) {
    float s = 0.f;
#pragma unroll
    for (int i = 0; i < 12; ++i) s += ssum_l[i * 16 + tid];
    const int t = t0 + tid;
    const int len = min(TOK, t + WIN + 1) - max(0, t - WIN);
    rcp_l[tid] = 1.0f / (s * (float)len);
  }

  f32x4 o[4] = {};
  const int c0 = js0 >> 5;
#pragma unroll
  for (int kc = 0; kc < 6; ++kc) {
    const bf16x8 pa =
        *(const bf16x8*)&Pg[(((size_t)qt * 6 + kc) * 16 + l15) * 32 + l4 * 8];
    const int cc = min(max(c0 + kc, 0), TOK / 32 - 1);  // clamp; P=0 masks
    const size_t vb = (size_t)cc * (EMB * 32);
#pragma unroll
    for (int n = 0; n < 4; ++n) {
      const int d = ds * 192 + w * 64 + n * 16 + l15;
      const bf16x8 vbf = *(const bf16x8*)&vT_p[vb + (size_t)d * 32 + l4 * 8];
      o[n] = __builtin_amdgcn_mfma_f32_16x16x32_bf16(pa, vbf, o[n], 0, 0, 0);
    }
  }
  __syncthreads();  // rcp_l ready

  const int qrow0 = t0 + l4 * 4;
  float rr[4];
#pragma unroll
  for (int r = 0; r < 4; ++r) rr[r] = rcp_l[l4 * 4 + r];
#pragma unroll
  for (int n = 0; n < 4; ++n) {
    const int d = ds * 192 + w * 64 + n * 16 + l15;
#pragma unroll
    for (int r = 0; r < 4; ++r)
      out[(size_t)(qrow0 + r) * EMB + d] = o[n][r] * rr[r];
  }
}

extern "C" void kernel_launch(void* const* d_in, const int* in_sizes, int n_in,
                              void* d_out, int out_size, void* d_ws, size_t ws_size,
                              hipStream_t stream) {
  const float* key = (const float*)d_in[0];
  const float* value = (const float*)d_in[1];
  const float* query = (const float*)d_in[2];
  const float* Wk = (const float*)d_in[3];
  const float* Wv = (const float*)d_in[4];
  const float* Wq = (const float*)d_in[5];

  // ws layout (~14 MB): WT | k_t | q_t | vT_p | Pg | Ssum
  unsigned short* ws = (unsigned short*)d_ws;
  const size_t NW = (size_t)3 * EMB * EMB;
  const size_t NM = (size_t)TOK * EMB;
  unsigned short* WT = ws;
  unsigned short* k_t = WT + NW;
  unsigned short* q_t = k_t + NM;
  unsigned short* vT_p = q_t + NM;
  unsigned short* Pg = vT_p + NM;                           // 393216 u16
  float* Ssum = (float*)(Pg + (size_t)128 * 6 * 16 * 32);   // 24576 f32
  float* out = (float*)d_out;

  cvt_wT<<<dim3(EMB / 32, EMB / 32, 3), dim3(32, 8), 0, stream>>>(
      Wk, Wv, Wq, WT);
  proj_gemm<<<dim3(EMB / 128, TOK / 64, 3), 256, 0, stream>>>(
      key, value, query, WT, k_t, vT_p, q_t);
  attn_S<<<512, 192, 0, stream>>>(k_t, q_t, Pg, Ssum);
  attn_PV<<<512, 192, 0, stream>>>(Pg, Ssum, vT_p, out);
}

// Round 10
// 42.902 us; speedup vs baseline: 1.3399x; 1.0901x over previous
//
#include <hip/hip_runtime.h>
#include <cstdint>

#define TOK 2048
#define EMB 768
#define WIN 64
#define TCN (TOK / 16) // 128 token tiles (16-row)
#define DCN (EMB / 32) // 24 d-chunks (32-col)

typedef __attribute__((ext_vector_type(8))) __bf16 bf16x8;
typedef __attribute__((ext_vector_type(4))) float f32x4;

static __device__ __forceinline__ unsigned short f2bf(float f) {
  uint32_t x = __float_as_uint(f);
  uint32_t r = (x + 0x7fffu + ((x >> 16) & 1u)) >> 16;  // RNE
  return (unsigned short)r;
}

static __device__ __forceinline__ void gload_lds16(const void* g, void* l) {
  __builtin_amdgcn_global_load_lds(
      (const __attribute__((address_space(1))) uint32_t*)g,
      (__attribute__((address_space(3))) uint32_t*)l, 16, 0, 0);
}

// ---------------- prep (merged): z=0 inputs->bf16, z=1 weights->WT ---------
__global__ __launch_bounds__(256) void prep(
    const float* __restrict__ key, const float* __restrict__ value,
    const float* __restrict__ query, const float* __restrict__ Wk,
    const float* __restrict__ Wv, const float* __restrict__ Wq,
    unsigned short* __restrict__ Ab, unsigned short* __restrict__ WT) {
  __shared__ float t[32][33];
  const int z = blockIdx.z, bx = blockIdx.x, tid = threadIdx.x;
  if (z == 0) {
    const int64_t NE4 = (int64_t)TOK * EMB / 4;  // float4 per input
    const int64_t i = (int64_t)bx * 256 + tid;   // grid sized exactly 3*NE4
    const int which = (int)(i / NE4);
    const int64_t loc = i - (int64_t)which * NE4;
    const float4* src =
        (const float4*)(which == 0 ? key : which == 1 ? value : query);
    const float4 x = src[loc];
    ushort4 h;
    h.x = f2bf(x.x); h.y = f2bf(x.y); h.z = f2bf(x.z); h.w = f2bf(x.w);
    ((ushort4*)Ab)[i] = h;
  } else {
    if (bx >= 1728) return;
    const int wz = bx / 576, rem = bx - wz * 576;
    const float* w = (wz == 0) ? Wk : (wz == 1) ? Wv : Wq;
    const int d0 = (rem % 24) * 32, e0 = (rem / 24) * 32;
    const int tx = tid & 31, ty = tid >> 5;  // (32,8)
#pragma unroll
    for (int r = 0; r < 4; ++r)
      t[ty + r * 8][tx] = w[(size_t)(e0 + ty + r * 8) * EMB + d0 + tx];
    __syncthreads();
#pragma unroll
    for (int r = 0; r < 4; ++r) {
      const int dl = ty + r * 8, el = tx;
      WT[(size_t)wz * EMB * EMB + (size_t)(d0 + dl) * EMB + e0 + el] =
          f2bf(t[el][dl]);
    }
  }
}

// ---------------- projections: bf16 MFMA GEMM, BK=64, double-buffered ------
// C = A@W. T3-lite: STAGE(next) issued before COMPUTE(cur); ONE barrier per
// K-step. BK=64 row stride = 128B -> 16-way bank conflict, fixed by T2 XOR
// involution: staging pre-swizzles the GLOBAL source column per lane
// (slot ^ row&7; gload_lds dest stays linear, rule #21), fragment read
// applies the same XOR -> 2-way (free).
// Epilogue writes MFMA-native layouts:
//   z=0 (k), z=2 (q): bf16 tiled [tok/16][d/32][16][32]
//   z=1 (v): bf16 V^T panels [tok/32][768][32]
__global__ __launch_bounds__(256) void proj_gemm(
    const unsigned short* __restrict__ Ab, const unsigned short* __restrict__ WT,
    unsigned short* __restrict__ k_t, unsigned short* __restrict__ vT_p,
    unsigned short* __restrict__ q_t) {
  const int z = blockIdx.z;
  const int bn0 = blockIdx.x * 128;  // output col (D)
  const int bm0 = blockIdx.y * 64;   // output row (token)
  const int tid = threadIdx.x, lane = tid & 63, w = tid >> 6;
  const int wr = w >> 1, wc = w & 1;
  const int l15 = lane & 15, l4 = lane >> 4;

  __shared__ unsigned short lA[2][64 * 64];    // 2 x 8KB
  __shared__ unsigned short lB[2][128 * 64];   // 2 x 16KB

  const unsigned short* __restrict__ Ah = Ab + (size_t)z * TOK * EMB;
  const unsigned short* __restrict__ Bh = WT + (size_t)z * EMB * EMB;

  f32x4 acc[2][4] = {};

  // staging: chunk ch covers rows ch*8..+8; lane -> (row, slot) with
  // source col pre-swizzled so lds slot s holds global chunk s^(row&7).
  const int srow = lane >> 3;                       // row within chunk group
  const int scol = ((lane & 7) ^ (srow & 7)) * 8;   // bf16 col (16B chunks)

  auto STAGE = [&](int b, int kt) {
    const int kk = kt * 64;
#pragma unroll
    for (int c = 0; c < 2; ++c) {
      const int ch = w * 2 + c;  // 8 A-chunks
      gload_lds16(Ah + (size_t)(bm0 + ch * 8 + srow) * EMB + kk + scol,
                  (char*)&lA[b][0] + ch * 1024);
    }
#pragma unroll
    for (int c = 0; c < 4; ++c) {
      const int ch = w * 4 + c;  // 16 B-chunks
      gload_lds16(Bh + (size_t)(bn0 + ch * 8 + srow) * EMB + kk + scol,
                  (char*)&lB[b][0] + ch * 1024);
    }
  };

  auto COMPUTE = [&](int b) {
#pragma unroll
    for (int ks = 0; ks < 2; ++ks) {
      bf16x8 af[2], bfr[4];
#pragma unroll
      for (int m = 0; m < 2; ++m) {
        const int R = wr * 32 + m * 16 + l15;
        const int sl = (ks * 4 + l4) ^ (R & 7);
        af[m] = *(const bf16x8*)((const char*)&lA[b][0] + R * 128 + sl * 16);
      }
#pragma unroll
      for (int n = 0; n < 4; ++n) {
        const int R = wc * 64 + n * 16 + l15;
        const int sl = (ks * 4 + l4) ^ (R & 7);
        bfr[n] = *(const bf16x8*)((const char*)&lB[b][0] + R * 128 + sl * 16);
      }
#pragma unroll
      for (int m = 0; m < 2; ++m)
#pragma unroll
        for (int n = 0; n < 4; ++n)
          acc[m][n] = __builtin_amdgcn_mfma_f32_16x16x32_bf16(af[m], bfr[n],
                                                              acc[m][n], 0, 0, 0);
    }
  };

  STAGE(0, 0);
  __syncthreads();  // prologue drain (vmcnt0 via barrier)
#pragma unroll
  for (int kt = 0; kt < 12; kt += 2) {
    if (kt + 1 < 12) STAGE(1, kt + 1);
    COMPUTE(0);
    __syncthreads();  // prefetch(1) drained; all reads of buf0 done
    if (kt + 2 < 12) STAGE(0, kt + 2);
    COMPUTE(1);
    __syncthreads();
  }

  // ---- epilogue: write MFMA-native layouts ----
  if (z == 1) {
#pragma unroll
    for (int m = 0; m < 2; ++m) {
      const int tok0 = bm0 + wr * 32 + m * 16 + l4 * 4;
#pragma unroll
      for (int n = 0; n < 4; ++n) {
        const int d = bn0 + wc * 64 + n * 16 + l15;
        ushort4 pk;
        pk.x = f2bf(acc[m][n][0]); pk.y = f2bf(acc[m][n][1]);
        pk.z = f2bf(acc[m][n][2]); pk.w = f2bf(acc[m][n][3]);
        *(ushort4*)&vT_p[(((size_t)(tok0 >> 5) * EMB + d) << 5) + (tok0 & 31)] = pk;
      }
    }
  } else {
    unsigned short* __restrict__ dh = (z == 0) ? k_t : q_t;
#pragma unroll
    for (int m = 0; m < 2; ++m) {
      const int tok0 = bm0 + wr * 32 + m * 16 + l4 * 4;
#pragma unroll
      for (int n = 0; n < 4; ++n) {
        const int d = bn0 + wc * 64 + n * 16 + l15;
        const size_t base =
            (((size_t)(tok0 >> 4) * DCN + (d >> 5)) * 16) * 32 + (d & 31);
#pragma unroll
        for (int r = 0; r < 4; ++r)
          dh[base + (size_t)((tok0 & 15) + r) * 32] = f2bf(acc[m][n][r]);
      }
    }
  }
}

// ---------------- attn stage 1: scores -> exp -> P tiles + partial sums ----
// grid 512 = (qt 0..127) x (ksplit 0..3); 3 waves, wave owns N-tile
// nt = ks*3+w of 12. No max-subtraction (scores ~N(0,1), exp safe in fp32).
// P -> A-tile layout [qt*6+c][16 q][32 slot] bf16; partial sums -> Ssum.
__global__ __launch_bounds__(192) void attn_S(
    const unsigned short* __restrict__ k_t, const unsigned short* __restrict__ q_t,
    unsigned short* __restrict__ Pg, float* __restrict__ Ssum) {
  const int bid = ((int)blockIdx.x & 7) * 64 + ((int)blockIdx.x >> 3);  // XCD swz
  const int qt = bid >> 2, ks = bid & 3;
  const int lane = threadIdx.x & 63, w = threadIdx.x >> 6;  // 0..2
  const int nt = ks * 3 + w;                                // 0..11
  const int l15 = lane & 15, l4 = lane >> 4;
  const int t0 = qt * 16;
  const int js0 = (t0 - 64) & ~31;  // 32-aligned slot base (maybe <0)
  const int foff = l15 * 32 + l4 * 8;

  const size_t a_base = (size_t)qt * DCN * 512 + foff;
  const int ttile = min(max((js0 >> 4) + nt, 0), TCN - 1);  // clamp; masked
  const size_t b_base = (size_t)ttile * DCN * 512 + foff;

  f32x4 s = {};
#pragma unroll 8
  for (int kk = 0; kk < DCN; ++kk) {
    const bf16x8 ah = *(const bf16x8*)&q_t[a_base + (size_t)kk * 512];
    const bf16x8 bh = *(const bf16x8*)&k_t[b_base + (size_t)kk * 512];
    s = __builtin_amdgcn_mfma_f32_16x16x32_bf16(ah, bh, s, 0, 0, 0);
  }

  const float SC = 0.03608439182435161f;  // 768^-0.5
  const int j = js0 + nt * 16 + l15;
  const int qrow0 = t0 + l4 * 4;
  const int c = nt >> 1, colb = (nt & 1) * 16 + l15;

  float e[4];
#pragma unroll
  for (int r = 0; r < 4; ++r) {
    const int t = qrow0 + r;
    const bool ok = (j >= 0) && (j < TOK) && (j >= t - WIN) && (j <= t + WIN);
    e[r] = ok ? __expf(s[r] * SC) : 0.0f;
  }
#pragma unroll
  for (int r = 0; r < 4; ++r) {
    float sm = e[r];
#pragma unroll
    for (int off = 1; off < 16; off <<= 1) sm += __shfl_xor(sm, off);
    if (l15 == 0) Ssum[qt * 192 + nt * 16 + l4 * 4 + r] = sm;
  }
#pragma unroll
  for (int r = 0; r < 4; ++r)
    Pg[(((size_t)qt * 6 + c) * 16 + (l4 * 4 + r)) * 32 + colb] = f2bf(e[r]);
}

// ---------------- attn stage 2: PV + normalize ----------------
// grid 512 = (qt 0..127) x (dsplit 0..3); 3 waves, wave owns 64 d-cols.
// out[q][d] = (sum_k P[q][k] V[k][d]) / (rowsum * L).
__global__ __launch_bounds__(192) void attn_PV(
    const unsigned short* __restrict__ Pg, const float* __restrict__ Ssum,
    const unsigned short* __restrict__ vT_p, float* __restrict__ out) {
  const int bid = ((int)blockIdx.x & 7) * 64 + ((int)blockIdx.x >> 3);  // XCD swz
  const int qt = bid >> 2, ds = bid & 3;
  const int tid = threadIdx.x;
  const int lane = tid & 63, w = tid >> 6;
  const int l15 = lane & 15, l4 = lane >> 4;
  const int t0 = qt * 16;
  const int js0 = (t0 - 64) & ~31;

  __shared__ float ssum_l[192];
  __shared__ float rcp_l[16];

  ssum_l[tid] = Ssum[qt * 192 + tid];
  __syncthreads();
  if (tid < 16) {
    float s = 0.f;
#pragma unroll
    for (int i = 0; i < 12; ++i) s += ssum_l[i * 16 + tid];
    const int t = t0 + tid;
    const int len = min(TOK, t + WIN + 1) - max(0, t - WIN);
    rcp_l[tid] = 1.0f / (s * (float)len);
  }

  f32x4 o[4] = {};
  const int c0 = js0 >> 5;
#pragma unroll
  for (int kc = 0; kc < 6; ++kc) {
    const bf16x8 pa =
        *(const bf16x8*)&Pg[(((size_t)qt * 6 + kc) * 16 + l15) * 32 + l4 * 8];
    const int cc = min(max(c0 + kc, 0), TOK / 32 - 1);  // clamp; P=0 masks
    const size_t vb = (size_t)cc * (EMB * 32);
#pragma unroll
    for (int n = 0; n < 4; ++n) {
      const int d = ds * 192 + w * 64 + n * 16 + l15;
      const bf16x8 vbf = *(const bf16x8*)&vT_p[vb + (size_t)d * 32 + l4 * 8];
      o[n] = __builtin_amdgcn_mfma_f32_16x16x32_bf16(pa, vbf, o[n], 0, 0, 0);
    }
  }
  __syncthreads();  // rcp_l ready

  const int qrow0 = t0 + l4 * 4;
  float rr[4];
#pragma unroll
  for (int r = 0; r < 4; ++r) rr[r] = rcp_l[l4 * 4 + r];
#pragma unroll
  for (int n = 0; n < 4; ++n) {
    const int d = ds * 192 + w * 64 + n * 16 + l15;
#pragma unroll
    for (int r = 0; r < 4; ++r)
      out[(size_t)(qrow0 + r) * EMB + d] = o[n][r] * rr[r];
  }
}

extern "C" void kernel_launch(void* const* d_in, const int* in_sizes, int n_in,
                              void* d_out, int out_size, void* d_ws, size_t ws_size,
                              hipStream_t stream) {
  const float* key = (const float*)d_in[0];
  const float* value = (const float*)d_in[1];
  const float* query = (const float*)d_in[2];
  const float* Wk = (const float*)d_in[3];
  const float* Wv = (const float*)d_in[4];
  const float* Wq = (const float*)d_in[5];

  // ws layout (~25 MB): Ab | WT | k_t | q_t | vT_p | Pg | Ssum
  unsigned short* ws = (unsigned short*)d_ws;
  const size_t NA = (size_t)3 * TOK * EMB;
  const size_t NW = (size_t)3 * EMB * EMB;
  const size_t NM = (size_t)TOK * EMB;
  unsigned short* Ab = ws;
  unsigned short* WT = Ab + NA;
  unsigned short* k_t = WT + NW;
  unsigned short* q_t = k_t + NM;
  unsigned short* vT_p = q_t + NM;
  unsigned short* Pg = vT_p + NM;                           // 393216 u16
  float* Ssum = (float*)(Pg + (size_t)128 * 6 * 16 * 32);   // 24576 f32
  float* out = (float*)d_out;

  prep<<<dim3(3 * TOK * EMB / 4 / 256, 1, 2), 256, 0, stream>>>(
      key, value, query, Wk, Wv, Wq, Ab, WT);
  proj_gemm<<<dim3(EMB / 128, TOK / 64, 3), 256, 0, stream>>>(
      Ab, WT, k_t, vT_p, q_t);
  attn_S<<<512, 192, 0, stream>>>(k_t, q_t, Pg, Ssum);
  attn_PV<<<512, 192, 0, stream>>>(Pg, Ssum, vT_p, out);
}